// Round 2
// baseline (6395.949 us; speedup 1.0000x reference)
//
#include <hip/hip_runtime.h>
#include <hip/hip_bf16.h>
#include <cstdint>
#include <cstddef>

typedef unsigned short u16;
typedef unsigned int u32;
typedef __attribute__((ext_vector_type(8))) short short8;   // 8 x bf16 (MFMA A/B frag)
typedef __attribute__((ext_vector_type(4))) float f32x4;    // MFMA C/D frag
typedef __attribute__((ext_vector_type(4))) float f4v;
typedef __attribute__((ext_vector_type(4))) u16 u16x4;

// B=64, T=128, I=512, H=256 (4H=1024), O=512
// ---------- helpers ----------
__device__ __forceinline__ u16 f2bf(float f) {
  u32 u = __float_as_uint(f);
  u32 r = (u + 0x7fffu + ((u >> 16) & 1u)) >> 16;   // RNE
  return (u16)r;
}
__device__ __forceinline__ float bf2f(u16 v) { return __uint_as_float(((u32)v) << 16); }
__device__ __forceinline__ float sigm(float x) { return 1.f / (1.f + __expf(-x)); }
__device__ __forceinline__ float tanh_(float x) {
  x = fminf(fmaxf(x, -30.f), 30.f);
  float e = __expf(-2.f * x);
  return (1.f - e) / (1.f + e);
}
// order-preserving f32 <-> u32 encode for atomicMax
__device__ __forceinline__ u32 encf(float f) {
  u32 u = __float_as_uint(f);
  return (u & 0x80000000u) ? ~u : (u | 0x80000000u);
}
__device__ __forceinline__ float decf(u32 u) {
  return __uint_as_float((u & 0x80000000u) ? (u & 0x7fffffffu) : ~u);
}

#define SWZ(row, kb) ((kb) ^ (((row) & 7) << 4))

// ---------- f32 -> bf16 convert (plain) ----------
__global__ void cvt_bf16_kernel(const float* __restrict__ src, u16* __restrict__ dst, int n4) {
  int i = blockIdx.x * blockDim.x + threadIdx.x;
  int stride = gridDim.x * blockDim.x;
  for (; i < n4; i += stride) {
    f4v v = *(const f4v*)(src + (size_t)i * 4);
    u16x4 o;
    o.x = f2bf(v.x); o.y = f2bf(v.y); o.z = f2bf(v.z); o.w = f2bf(v.w);
    *(u16x4*)(dst + (size_t)i * 4) = o;
  }
}

// ---------- split input: x[8192,512] f32 -> XH[8192,1536] = [x_hi | x_lo | x_hi] ----------
__global__ void split_input_kernel(const float* __restrict__ src, u16* __restrict__ dst, int total) {
  int idx = blockIdx.x * blockDim.x + threadIdx.x;
  int stride = gridDim.x * blockDim.x;
  for (; idx < total; idx += stride) {
    int r = idx >> 9, c = idx & 511;
    float x = src[idx];
    u16 hi = f2bf(x);
    u16 lo = f2bf(x - bf2f(hi));
    u16* d = dst + (size_t)r * 1536;
    d[c] = hi; d[512 + c] = lo; d[1024 + c] = hi;
  }
}
// ---------- split weight: W[1024,512] f32 -> W2[1024,1536] = [W_hi | W_hi | W_lo] ----------
__global__ void split_w_kernel(const float* __restrict__ src, u16* __restrict__ dst) {
  int idx = blockIdx.x * blockDim.x + threadIdx.x;  // 524288 exact
  int r = idx >> 9, c = idx & 511;
  float x = src[idx];
  u16 hi = f2bf(x);
  u16 lo = f2bf(x - bf2f(hi));
  u16* d = dst + (size_t)r * 1536;
  d[c] = hi; d[512 + c] = hi; d[1024 + c] = lo;
}

__global__ void zero_u32_kernel(u32* __restrict__ p, int n) {
  int i = blockIdx.x * blockDim.x + threadIdx.x;
  int stride = gridDim.x * blockDim.x;
  for (; i < n; i += stride) p[i] = 0u;
}

// ---------- bf16 GEMM: C[M,N] = A[M,K](lda) @ W[N,K](ldw)^T + bias[N], C fp32 ----------
// BM=128, BN=128, BK=64; 256 threads = 4 waves (2x2 wave grid, 64x64 per wave)
__global__ __launch_bounds__(256, 1) void gemm_bt_kernel(
    const u16* __restrict__ A, int lda, const u16* __restrict__ W, int ldw,
    const float* __restrict__ bias, float* __restrict__ C,
    int M, int N, int K) {
  __shared__ __align__(16) u16 As[128 * 64];
  __shared__ __align__(16) u16 Bs[128 * 64];
  const int m0 = blockIdx.y * 128, n0 = blockIdx.x * 128;
  const int tid = threadIdx.x;
  const int w = tid >> 6, l = tid & 63;
  const int wr = w >> 1, wc = w & 1;
  const int lhi = l >> 4, llo = l & 15;

  f32x4 acc[4][4];
#pragma unroll
  for (int a = 0; a < 4; ++a)
#pragma unroll
    for (int b = 0; b < 4; ++b) acc[a][b] = (f32x4){0.f, 0.f, 0.f, 0.f};

  for (int k0 = 0; k0 < K; k0 += 64) {
    __syncthreads();
#pragma unroll
    for (int it = 0; it < 4; ++it) {
      int off = it * 4096 + tid * 16;
      int row = off >> 7, kb = off & 127;
      short8 va = *(const short8*)((const char*)A + ((size_t)(m0 + row) * lda + k0) * 2 + kb);
      *(short8*)((char*)As + row * 128 + SWZ(row, kb)) = va;
      short8 vb = *(const short8*)((const char*)W + ((size_t)(n0 + row) * ldw + k0) * 2 + kb);
      *(short8*)((char*)Bs + row * 128 + SWZ(row, kb)) = vb;
    }
    __syncthreads();
    short8 af[4][2], bf[4][2];
#pragma unroll
    for (int mt = 0; mt < 4; ++mt)
#pragma unroll
      for (int ks = 0; ks < 2; ++ks) {
        int row = wr * 64 + mt * 16 + llo;
        int kb = ks * 64 + lhi * 16;
        af[mt][ks] = *(const short8*)((const char*)As + row * 128 + SWZ(row, kb));
      }
#pragma unroll
    for (int nt = 0; nt < 4; ++nt)
#pragma unroll
      for (int ks = 0; ks < 2; ++ks) {
        int row = wc * 64 + nt * 16 + llo;
        int kb = ks * 64 + lhi * 16;
        bf[nt][ks] = *(const short8*)((const char*)Bs + row * 128 + SWZ(row, kb));
      }
#pragma unroll
    for (int ks = 0; ks < 2; ++ks)
#pragma unroll
      for (int mt = 0; mt < 4; ++mt)
#pragma unroll
        for (int nt = 0; nt < 4; ++nt)
          acc[mt][nt] = __builtin_amdgcn_mfma_f32_16x16x32_bf16(af[mt][ks], bf[nt][ks], acc[mt][nt], 0, 0, 0);
  }
#pragma unroll
  for (int mt = 0; mt < 4; ++mt)
#pragma unroll
    for (int nt = 0; nt < 4; ++nt) {
      int col = n0 + wc * 64 + nt * 16 + llo;
      float bz = bias ? bias[col] : 0.f;
#pragma unroll
      for (int i = 0; i < 4; ++i) {
        int row = m0 + wr * 64 + mt * 16 + lhi * 4 + i;
        C[(size_t)row * N + col] = acc[mt][nt][i] + bz;
      }
    }
}

// ---------- LSTM scan ----------
// Each block owns 16 batch rows of one run; loops over its time window locally.
// Per step: gates[16,1024] = h[16,256] @ Whh[1024,256]^T + xp[:,t,:]; cell update.
// 4 waves: wave w owns hidden channels [w*64, w*64+64) (x 4 gates).
// phase 1: 208 blocks. fwd blocks 0..103: run j=0..25 x4 batch-quarters; bwd 104..207.
//   run 0 (full): store h -> out (HFfull/HBfull, [bt][256]).
//   fwd run j>=1 (suffix, t=j..127): atomicMax into NIenc at flat=(j-1)*512+ch.
//   bwd run r>=1 (prefix, t=r-1..0): atomicMax at flat=(r-1)*512+256+ch.
// phase 2: 8 blocks; store h -> REC [bt][512] (bwd pointer pre-offset by 256).
__global__ __launch_bounds__(256, 1) void scan_kernel(
    const u16* __restrict__ Wf, const u16* __restrict__ Wb,
    const float* __restrict__ xpF, const float* __restrict__ xpB,
    u16* __restrict__ outF, u16* __restrict__ outB,
    u32* __restrict__ NIenc, int phase) {
  __shared__ __align__(16) u16 hlds[16 * 256];
  const int bid = blockIdx.x;
  const int nb = (phase == 1) ? 104 : 4;
  const bool fwd = bid < nb;
  const int id = fwd ? bid : bid - nb;
  const int run = (phase == 1) ? (id >> 2) : 0;
  const int q = (phase == 1) ? (id & 3) : id;
  const int qbase = q * 16;
  const u16* W = fwd ? Wf : Wb;
  const float* xp = fwd ? xpF : xpB;
  u16* out = fwd ? outF : outB;
  const int ostride = (phase == 1) ? 256 : 512;
  const bool store_out = (phase == 2) || (run == 0);
  const u32 flatbase = (u32)(run - 1) * 512u + (fwd ? 0u : 256u);  // only used when !store_out
  int t0, tstep, nsteps;
  if (fwd) {
    t0 = (phase == 1) ? run : 0; tstep = 1; nsteps = 128 - t0;
  } else {
    int s = (phase == 1) ? (run == 0 ? 127 : run - 1) : 127;
    t0 = s; tstep = -1; nsteps = s + 1;
  }
  const int w = threadIdx.x >> 6, l = threadIdx.x & 63;
  const int lhi = l >> 4, llo = l & 15;

  for (int i = threadIdx.x; i < 16 * 256; i += 256) hlds[i] = 0;
  float cst[16];
#pragma unroll
  for (int i = 0; i < 16; ++i) cst[i] = 0.f;
  __syncthreads();

  int t = t0;
  for (int it = 0; it < nsteps; ++it, t += tstep) {
    // A fragments: h[16 rows, 256 k] from swizzled LDS
    short8 af[8];
#pragma unroll
    for (int ks = 0; ks < 8; ++ks) {
      int kb = ks * 64 + lhi * 16;
      af[ks] = *(const short8*)((const char*)hlds + llo * 512 + SWZ(llo, kb));
    }
    // init acc from xp (bias already folded into xp)
    f32x4 acc[16];
#pragma unroll
    for (int T = 0; T < 16; ++T) {
      int g = T >> 2, s = T & 3;
      int n = g * 256 + w * 64 + s * 16 + llo;
#pragma unroll
      for (int i = 0; i < 4; ++i) {
        int b = qbase + lhi * 4 + i;
        acc[T][i] = xp[((size_t)b * 128 + t) * 1024 + n];
      }
    }
    // stream W tiles from global (L2-resident), double-buffered in regs
    short8 bfr[2][8];
    {
      int n = w * 64 + llo;  // tile 0: g=0, s=0
#pragma unroll
      for (int ks = 0; ks < 8; ++ks)
        bfr[0][ks] = *(const short8*)((const char*)W + (size_t)n * 512 + ks * 64 + lhi * 16);
    }
#pragma unroll
    for (int T = 0; T < 16; ++T) {
      if (T < 15) {
        int Tn = T + 1;
        int n = (Tn >> 2) * 256 + w * 64 + (Tn & 3) * 16 + llo;
#pragma unroll
        for (int ks = 0; ks < 8; ++ks)
          bfr[Tn & 1][ks] = *(const short8*)((const char*)W + (size_t)n * 512 + ks * 64 + lhi * 16);
      }
#pragma unroll
      for (int ks = 0; ks < 8; ++ks)
        acc[T] = __builtin_amdgcn_mfma_f32_16x16x32_bf16(af[ks], bfr[T & 1][ks], acc[T], 0, 0, 0);
    }
    // cell update (f32)
    float hv[16];
#pragma unroll
    for (int s = 0; s < 4; ++s)
#pragma unroll
      for (int i = 0; i < 4; ++i) {
        float ig = sigm(acc[0 + s][i]);
        float fg = sigm(acc[4 + s][i]);
        float gg = tanh_(acc[8 + s][i]);
        float og = sigm(acc[12 + s][i]);
        float c = fg * cst[s * 4 + i] + ig * gg;
        cst[s * 4 + i] = c;
        hv[s * 4 + i] = og * tanh_(c);
      }
    __syncthreads();  // all waves done reading hlds
#pragma unroll
    for (int s = 0; s < 4; ++s)
#pragma unroll
      for (int i = 0; i < 4; ++i) {
        int row = lhi * 4 + i;
        int ch = w * 64 + s * 16 + llo;
        float h = hv[s * 4 + i];
        u16 hb = f2bf(h);
        *(u16*)((char*)hlds + ((row * 512 + ch * 2) ^ ((row & 7) << 4))) = hb;
        int b = qbase + row;
        if (store_out) {
          out[((size_t)b * 128 + t) * ostride + ch] = hb;
        } else {
          u32 flat = flatbase + (u32)ch;
          u32 qq = (flat * 5243u) >> 17;  // flat / 25
          atomicMax(&NIenc[(size_t)((size_t)b * 128 + t) * 512 + qq], encf(h));
        }
      }
    __syncthreads();
  }
}

// ---------- finish: merge full-run contributions + decode -> NI bf16 ----------
// NI[b,t,q] = max( dec(NIenc[bt,q]), full-run slots in window [q*25, q*25+25) )
// slot flat=k*512+c: c<256 & t<=k -> HFfull[bt,c]; c>=256 & t>k -> HBfull[bt,c-256]
__global__ void finish_kernel(const u32* __restrict__ NIenc,
                              const u16* __restrict__ HFfull, const u16* __restrict__ HBfull,
                              u16* __restrict__ NI) {
  const int bt = blockIdx.x;      // b*128 + t
  const int t = bt & 127;
  const int qidx = threadIdx.x;   // 0..511
  float m = decf(NIenc[(size_t)bt * 512 + qidx]);
  const int base = qidx * 25;
#pragma unroll
  for (int r = 0; r < 25; ++r) {
    int idx = base + r;
    int k = idx >> 9;
    int c = idx & 511;
    if (c < 256) {
      if (t <= k) m = fmaxf(m, bf2f(HFfull[(size_t)bt * 256 + c]));
    } else {
      if (t > k) m = fmaxf(m, bf2f(HBfull[(size_t)bt * 256 + (c - 256)]));
    }
  }
  NI[(size_t)bt * 512 + qidx] = f2bf(m);
}

// ---------- host ----------
extern "C" void kernel_launch(void* const* d_in, const int* in_sizes, int n_in,
                              void* d_out, int out_size, void* d_ws, size_t ws_size,
                              hipStream_t stream) {
  (void)in_sizes; (void)n_in; (void)out_size; (void)ws_size;
  const float* input  = (const float*)d_in[0];
  const float* w_ih_f = (const float*)d_in[1];
  const float* w_hh_f = (const float*)d_in[2];
  const float* b_f    = (const float*)d_in[3];
  const float* w_ih_b = (const float*)d_in[4];
  const float* w_hh_b = (const float*)d_in[5];
  const float* b_b    = (const float*)d_in[6];
  const float* W_lin  = (const float*)d_in[7];
  const float* b_lin  = (const float*)d_in[8];

  char* ws = (char*)d_ws;
  size_t off = 0;
  auto alloc = [&](size_t bytes) {
    char* p = ws + off;
    off = (off + bytes + 255) & ~(size_t)255;
    return p;
  };
  // total ~112 MiB
  u16* WIH2F = (u16*)alloc(3145728);   // [1024,1536] = [W_hi|W_hi|W_lo]
  u16* WIH2B = (u16*)alloc(3145728);
  u16* WHHF  = (u16*)alloc(524288);    // [1024,256]
  u16* WHHB  = (u16*)alloc(524288);
  u16* WLIN  = (u16*)alloc(524288);    // [512,512]
  float* XPF = (float*)alloc(33554432);  // [64,128,1024] f32 (reused as XP2F)
  float* XPB = (float*)alloc(33554432);  //               (reused as XP2B)
  u16* NIbf  = (u16*)alloc(8388608);   // [8192,512] bf16
  u16* HFfull = (u16*)alloc(4194304);  // [8192,256] bf16  (later aliased as REC lower half)
  u16* HBfull = (u16*)alloc(4194304);  // [8192,256] bf16  (REC upper half — contiguous with HFfull)
  u16* XH    = (u16*)alloc(25165824);  // [8192,1536] = [x_hi|x_lo|x_hi]
  u32* NIenc = (u32*)XH;               // [8192,512] u32 (16 MB) — aliases XH (dead by then)
  u16* REC   = HFfull;                 // [8192,512] bf16 — aliases HFfull+HBfull (dead by then)

  // --- weight prep + input split ---
  split_input_kernel<<<dim3(4096), dim3(256), 0, stream>>>(input, XH, 4194304);
  split_w_kernel<<<dim3(2048), dim3(256), 0, stream>>>(w_ih_f, WIH2F);
  split_w_kernel<<<dim3(2048), dim3(256), 0, stream>>>(w_ih_b, WIH2B);
  cvt_bf16_kernel<<<dim3(256), dim3(256), 0, stream>>>(w_hh_f, WHHF, 65536);
  cvt_bf16_kernel<<<dim3(256), dim3(256), 0, stream>>>(w_hh_b, WHHB, 65536);
  cvt_bf16_kernel<<<dim3(256), dim3(256), 0, stream>>>(W_lin, WLIN, 65536);

  // --- stage-1 xp (split precision): xp = x_hi@W + x_lo@W_hi + b ---
  gemm_bt_kernel<<<dim3(8, 64), dim3(256), 0, stream>>>(XH, 1536, WIH2F, 1536, b_f, XPF, 8192, 1024, 1536);
  gemm_bt_kernel<<<dim3(8, 64), dim3(256), 0, stream>>>(XH, 1536, WIH2B, 1536, b_b, XPB, 8192, 1024, 1536);

  // --- NIenc init (XH now dead) ---
  zero_u32_kernel<<<dim3(4096), dim3(256), 0, stream>>>(NIenc, 4194304);

  // --- stage-1 scans: full runs store, variant runs atomic-max into NIenc ---
  scan_kernel<<<dim3(208), dim3(256), 0, stream>>>(WHHF, WHHB, XPF, XPB, HFfull, HBfull, NIenc, 1);

  // --- merge full-run slots, decode -> NI bf16 ---
  finish_kernel<<<dim3(8192), dim3(512), 0, stream>>>(NIenc, HFfull, HBfull, NIbf);

  // --- stage-3 xp over new_input (plain bf16; W_hi = cols 0..511 of WIH2) ---
  gemm_bt_kernel<<<dim3(8, 64), dim3(256), 0, stream>>>(NIbf, 512, WIH2F, 1536, b_f, XPF, 8192, 1024, 512);
  gemm_bt_kernel<<<dim3(8, 64), dim3(256), 0, stream>>>(NIbf, 512, WIH2B, 1536, b_b, XPB, 8192, 1024, 512);

  // --- stage-3 bidirectional scan -> REC[bt][512] (fwd ch 0..255, bwd 256..511) ---
  scan_kernel<<<dim3(8), dim3(256), 0, stream>>>(WHHF, WHHB, XPF, XPB, REC, REC + 256, NIenc, 2);

  // --- output = REC @ W_lin^T + b_lin ---
  gemm_bt_kernel<<<dim3(4, 64), dim3(256), 0, stream>>>(REC, 512, WLIN, 512, b_lin, (float*)d_out, 8192, 512, 512);
}

// Round 4
// 3318.768 us; speedup vs baseline: 1.9272x; 1.9272x over previous
//
#include <hip/hip_runtime.h>
#include <hip/hip_bf16.h>
#include <cstdint>
#include <cstddef>

typedef unsigned short u16;
typedef unsigned int u32;
typedef __attribute__((ext_vector_type(8))) short short8;   // 8 x bf16 (MFMA A/B frag)
typedef __attribute__((ext_vector_type(4))) float f32x4;    // MFMA C/D frag
typedef __attribute__((ext_vector_type(4))) float f4v;
typedef __attribute__((ext_vector_type(4))) u16 u16x4;

// B=64, T=128, I=512, H=256 (4H=1024), O=512
__device__ __forceinline__ u16 f2bf(float f) {
  u32 u = __float_as_uint(f);
  u32 r = (u + 0x7fffu + ((u >> 16) & 1u)) >> 16;   // RNE
  return (u16)r;
}
__device__ __forceinline__ float bf2f(u16 v) { return __uint_as_float(((u32)v) << 16); }
__device__ __forceinline__ float sigm(float x) { return 1.f / (1.f + __expf(-x)); }
__device__ __forceinline__ float tanh_(float x) {
  x = fminf(fmaxf(x, -30.f), 30.f);
  float e = __expf(-2.f * x);
  return (1.f - e) / (1.f + e);
}

#define SWZ(row, kb) ((kb) ^ (((row) & 7) << 4))

// ---------- f32 -> bf16 convert ----------
__global__ void cvt_bf16_kernel(const float* __restrict__ src, u16* __restrict__ dst, int n4) {
  int i = blockIdx.x * blockDim.x + threadIdx.x;
  int stride = gridDim.x * blockDim.x;
  for (; i < n4; i += stride) {
    f4v v = *(const f4v*)(src + (size_t)i * 4);
    u16x4 o;
    o.x = f2bf(v.x); o.y = f2bf(v.y); o.z = f2bf(v.z); o.w = f2bf(v.w);
    *(u16x4*)(dst + (size_t)i * 4) = o;
  }
}

// ---------- split input: x[8192,512] f32 -> XH[8192,1536] = [x_hi | x_lo | x_hi] ----------
__global__ void split_input_kernel(const float* __restrict__ src, u16* __restrict__ dst, int total) {
  int idx = blockIdx.x * blockDim.x + threadIdx.x;
  int stride = gridDim.x * blockDim.x;
  for (; idx < total; idx += stride) {
    int r = idx >> 9, c = idx & 511;
    float x = src[idx];
    u16 hi = f2bf(x);
    u16 lo = f2bf(x - bf2f(hi));
    u16* d = dst + (size_t)r * 1536;
    d[c] = hi; d[512 + c] = lo; d[1024 + c] = hi;
  }
}
// ---------- split weight: W[1024,512] f32 -> dst rows [W_hi | W_hi | W_lo] ----------
__global__ void split_w_kernel(const float* __restrict__ src, u16* __restrict__ dst) {
  int idx = blockIdx.x * blockDim.x + threadIdx.x;  // 524288 exact
  int r = idx >> 9, c = idx & 511;
  float x = src[idx];
  u16 hi = f2bf(x);
  u16 lo = f2bf(x - bf2f(hi));
  u16* d = dst + (size_t)r * 1536;
  d[c] = hi; d[512 + c] = hi; d[1024 + c] = lo;
}

__global__ void fill_u32_kernel(u32* __restrict__ p, u32 val, int n) {
  int i = blockIdx.x * blockDim.x + threadIdx.x;
  int stride = gridDim.x * blockDim.x;
  for (; i < n; i += stride) p[i] = val;
}

// ---------- bf16 GEMM, split-N epilogue ----------
// C[M,Ntot] = A[M,K](lda) @ W[Ntot,K](ldw)^T; cols < nsplit -> C0 (+b0), else C1 (+b1).
// Both C have row stride nsplit. BM=BN=128, BK=64; 256 thr = 4 waves (2x2).
__global__ __launch_bounds__(256, 1) void gemm_bt_kernel(
    const u16* __restrict__ A, int lda, const u16* __restrict__ W, int ldw,
    const float* __restrict__ b0, const float* __restrict__ b1,
    float* __restrict__ C0, float* __restrict__ C1, int nsplit,
    int M, int K) {
  __shared__ __align__(16) u16 As[128 * 64];
  __shared__ __align__(16) u16 Bs[128 * 64];
  const int m0 = blockIdx.y * 128, n0 = blockIdx.x * 128;
  const int tid = threadIdx.x;
  const int w = tid >> 6, l = tid & 63;
  const int wr = w >> 1, wc = w & 1;
  const int lhi = l >> 4, llo = l & 15;

  f32x4 acc[4][4];
#pragma unroll
  for (int a = 0; a < 4; ++a)
#pragma unroll
    for (int b = 0; b < 4; ++b) acc[a][b] = (f32x4){0.f, 0.f, 0.f, 0.f};

  for (int k0 = 0; k0 < K; k0 += 64) {
    __syncthreads();
#pragma unroll
    for (int it = 0; it < 4; ++it) {
      int off = it * 4096 + tid * 16;
      int row = off >> 7, kb = off & 127;
      short8 va = *(const short8*)((const char*)A + ((size_t)(m0 + row) * lda + k0) * 2 + kb);
      *(short8*)((char*)As + row * 128 + SWZ(row, kb)) = va;
      short8 vb = *(const short8*)((const char*)W + ((size_t)(n0 + row) * ldw + k0) * 2 + kb);
      *(short8*)((char*)Bs + row * 128 + SWZ(row, kb)) = vb;
    }
    __syncthreads();
    short8 af[4][2], bf[4][2];
#pragma unroll
    for (int mt = 0; mt < 4; ++mt)
#pragma unroll
      for (int ks = 0; ks < 2; ++ks) {
        int row = wr * 64 + mt * 16 + llo;
        int kb = ks * 64 + lhi * 16;
        af[mt][ks] = *(const short8*)((const char*)As + row * 128 + SWZ(row, kb));
      }
#pragma unroll
    for (int nt = 0; nt < 4; ++nt)
#pragma unroll
      for (int ks = 0; ks < 2; ++ks) {
        int row = wc * 64 + nt * 16 + llo;
        int kb = ks * 64 + lhi * 16;
        bf[nt][ks] = *(const short8*)((const char*)Bs + row * 128 + SWZ(row, kb));
      }
#pragma unroll
    for (int ks = 0; ks < 2; ++ks)
#pragma unroll
      for (int mt = 0; mt < 4; ++mt)
#pragma unroll
        for (int nt = 0; nt < 4; ++nt)
          acc[mt][nt] = __builtin_amdgcn_mfma_f32_16x16x32_bf16(af[mt][ks], bf[nt][ks], acc[mt][nt], 0, 0, 0);
  }
#pragma unroll
  for (int mt = 0; mt < 4; ++mt)
#pragma unroll
    for (int nt = 0; nt < 4; ++nt) {
      int col = n0 + wc * 64 + nt * 16 + llo;
      const float* bp; float* Cp; int cc;
      if (col < nsplit) { bp = b0; Cp = C0; cc = col; }
      else              { bp = b1; Cp = C1; cc = col - nsplit; }
      float bz = bp[cc];
#pragma unroll
      for (int i = 0; i < 4; ++i) {
        int row = m0 + wr * 64 + mt * 16 + lhi * 4 + i;
        Cp[(size_t)row * nsplit + cc] = acc[mt][nt][i] + bz;
      }
    }
}

// ---------- LSTM scan (8 waves / 512 threads per block, 16 batch rows) ----------
// Wave w owns h-channels [w*32, w*32+32): 8 MFMA tiles (4 gates x 2 col-halves), K=256.
// W streamed from L2 with 2-tile-deep register pipeline (16 loads in flight).
// Variant runs: per-step per-row window maxes written NON-atomically to pA/pB (bf16):
//   window q owned-for-A by the source containing flat q*25; owned-for-B by the source
//   containing flat q*25+24 when that's a different source. Sources partition flat space.
__global__ __launch_bounds__(512, 1) void scan_kernel(
    const u16* __restrict__ Wf, const u16* __restrict__ Wb,
    const float* __restrict__ xpF, const float* __restrict__ xpB,
    u16* __restrict__ outF, u16* __restrict__ outB,
    u16* __restrict__ pA, u16* __restrict__ pB, int phase) {
  __shared__ __align__(16) u16 hlds[16 * 256];
  const int bid = blockIdx.x;
  const int nb = (phase == 1) ? 104 : 4;
  const bool fwd = bid < nb;
  const int id = fwd ? bid : bid - nb;
  const int run = (phase == 1) ? (id >> 2) : 0;
  const int q4 = (phase == 1) ? (id & 3) : id;
  const int qbase = q4 * 16;
  const u16* W = fwd ? Wf : Wb;
  const float* xp = fwd ? xpF : xpB;
  u16* out = fwd ? outF : outB;
  const int ostride = (phase == 1) ? 256 : 512;
  const bool store_out = (phase == 2) || (run == 0);
  const int flatbase = store_out ? 0 : ((run - 1) * 512 + (fwd ? 0 : 256));
  const int qlo = (flatbase * 5243) >> 17;
  const int qhi = ((flatbase + 255) * 5243) >> 17;
  int t0, tstep, nsteps;
  if (fwd) {
    t0 = (phase == 1) ? run : 0; tstep = 1; nsteps = 128 - t0;
  } else {
    int s = (phase == 1) ? (run == 0 ? 127 : run - 1) : 127;
    t0 = s; tstep = -1; nsteps = s + 1;
  }
  const int tid = threadIdx.x;
  const int w = tid >> 6, l = tid & 63;
  const int lhi = l >> 4, llo = l & 15;
  const int wrow = tid / 12, wq = tid - wrow * 12;   // wmax role: tid<192

  for (int i = tid; i < 16 * 256; i += 512) hlds[i] = 0;
  float cst[8];
#pragma unroll
  for (int i = 0; i < 8; ++i) cst[i] = 0.f;
  __syncthreads();

  // per-lane W base: rows n = nbase + w*32 + llo, bytes lhi*16 within 64B k-slices
  const char* Wl = (const char*)W + (size_t)(w * 32 + llo) * 512 + lhi * 16;

  int t = t0, tprev = t0;
  for (int it = 0; it < nsteps; ++it, t += tstep) {
    // ---- xp loads first (latency hides under prologue) ----
    f32x4 acc[8];
    {
      const float* xpl = xp + ((size_t)(qbase + lhi * 4) * 128 + t) * 1024 + w * 32 + llo;
#pragma unroll
      for (int tt = 0; tt < 8; ++tt) {
        int nofs = (tt >> 1) * 256 + (tt & 1) * 16;
#pragma unroll
        for (int i = 0; i < 4; ++i)
          acc[tt][i] = xpl[(size_t)i * 131072 + nofs];
      }
    }
    // ---- A fragments from LDS (h(t-1)) ----
    short8 af[8];
#pragma unroll
    for (int ks = 0; ks < 8; ++ks) {
      int kb = ks * 64 + lhi * 16;
      af[ks] = *(const short8*)((const char*)hlds + llo * 512 + SWZ(llo, kb));
    }
    // ---- window-max of previous step's h (reads hlds, h(t-1)) ----
    if (!store_out && it > 0 && tid < 192) {
      int q = qlo + wq;
      if (q <= qhi) {
        int lo = q * 25 - flatbase;
        int chlo = lo < 0 ? 0 : lo;
        int chhi = (lo + 24) > 255 ? 255 : (lo + 24);
        float m = -3.4e38f;
        for (int ch = chlo; ch <= chhi; ++ch)
          m = fmaxf(m, bf2f(*(const u16*)((const char*)hlds + ((wrow * 512 + ch * 2) ^ ((wrow & 7) << 4)))));
        u16* dst = (lo < 0) ? pB : pA;
        dst[(size_t)((qbase + wrow) * 128 + tprev) * 512 + q] = f2bf(m);
      }
    }
    // ---- W stream: 2-tile-deep pipeline, 8 tiles x 8 k-slices ----
    short8 bufA[8], bufB[8];
#pragma unroll
    for (int ks = 0; ks < 8; ++ks)
      bufA[ks] = *(const short8*)(Wl + (size_t)ks * 64);              // tile 0 (nbase 0)
#pragma unroll
    for (int ks = 0; ks < 8; ++ks)
      bufB[ks] = *(const short8*)(Wl + (size_t)16 * 512 + ks * 64);   // tile 1 (nbase 16)
#pragma unroll
    for (int tt = 0; tt < 8; ++tt) {
      int nb2 = ((tt + 2) >> 1) * 256 + ((tt + 2) & 1) * 16;          // prefetch tile tt+2
#pragma unroll
      for (int ks = 0; ks < 8; ++ks) {
        if (tt & 1) {
          acc[tt] = __builtin_amdgcn_mfma_f32_16x16x32_bf16(af[ks], bufB[ks], acc[tt], 0, 0, 0);
          if (tt < 6) bufB[ks] = *(const short8*)(Wl + (size_t)nb2 * 512 + ks * 64);
        } else {
          acc[tt] = __builtin_amdgcn_mfma_f32_16x16x32_bf16(af[ks], bufA[ks], acc[tt], 0, 0, 0);
          if (tt < 6) bufA[ks] = *(const short8*)(Wl + (size_t)nb2 * 512 + ks * 64);
        }
      }
    }
    // ---- cell update ----
    float hv[8];
#pragma unroll
    for (int hf = 0; hf < 2; ++hf)
#pragma unroll
      for (int i = 0; i < 4; ++i) {
        float ig = sigm(acc[0 + hf][i]);
        float fg = sigm(acc[2 + hf][i]);
        float gg = tanh_(acc[4 + hf][i]);
        float og = sigm(acc[6 + hf][i]);
        float c = fg * cst[hf * 4 + i] + ig * gg;
        cst[hf * 4 + i] = c;
        hv[hf * 4 + i] = og * tanh_(c);
      }
    __syncthreads();   // all reads of h(t-1) done
#pragma unroll
    for (int hf = 0; hf < 2; ++hf)
#pragma unroll
      for (int i = 0; i < 4; ++i) {
        int row = lhi * 4 + i;
        int ch = w * 32 + hf * 16 + llo;
        u16 hb = f2bf(hv[hf * 4 + i]);
        *(u16*)((char*)hlds + ((row * 512 + ch * 2) ^ ((row & 7) << 4))) = hb;
        if (store_out)
          out[((size_t)(qbase + row) * 128 + t) * ostride + ch] = hb;
      }
    __syncthreads();   // h(t) visible
    tprev = t;
  }
  // epilogue: window-max of the final step
  if (!store_out && tid < 192) {
    int q = qlo + wq;
    if (q <= qhi) {
      int lo = q * 25 - flatbase;
      int chlo = lo < 0 ? 0 : lo;
      int chhi = (lo + 24) > 255 ? 255 : (lo + 24);
      float m = -3.4e38f;
      for (int ch = chlo; ch <= chhi; ++ch)
        m = fmaxf(m, bf2f(*(const u16*)((const char*)hlds + ((wrow * 512 + ch * 2) ^ ((wrow & 7) << 4)))));
      u16* dst = (lo < 0) ? pB : pA;
      dst[(size_t)((qbase + wrow) * 128 + tprev) * 512 + q] = f2bf(m);
    }
  }
}

// ---------- finish: NI = max(pA, pB, full-run slots) ----------
__global__ void finish_kernel(const u16* __restrict__ pA, const u16* __restrict__ pB,
                              const u16* __restrict__ HFfull, const u16* __restrict__ HBfull,
                              u16* __restrict__ NI) {
  const int bt = blockIdx.x;      // b*128 + t
  const int t = bt & 127;
  const int qidx = threadIdx.x;   // 0..511
  float m = fmaxf(bf2f(pA[(size_t)bt * 512 + qidx]), bf2f(pB[(size_t)bt * 512 + qidx]));
  const int base = qidx * 25;
#pragma unroll
  for (int r = 0; r < 25; ++r) {
    int idx = base + r;
    int k = idx >> 9;
    int c = idx & 511;
    if (c < 256) {
      if (t <= k) m = fmaxf(m, bf2f(HFfull[(size_t)bt * 256 + c]));
    } else {
      if (t > k) m = fmaxf(m, bf2f(HBfull[(size_t)bt * 256 + (c - 256)]));
    }
  }
  NI[(size_t)bt * 512 + qidx] = f2bf(m);
}

// ---------- host ----------
extern "C" void kernel_launch(void* const* d_in, const int* in_sizes, int n_in,
                              void* d_out, int out_size, void* d_ws, size_t ws_size,
                              hipStream_t stream) {
  (void)in_sizes; (void)n_in; (void)out_size; (void)ws_size;
  const float* input  = (const float*)d_in[0];
  const float* w_ih_f = (const float*)d_in[1];
  const float* w_hh_f = (const float*)d_in[2];
  const float* b_f    = (const float*)d_in[3];
  const float* w_ih_b = (const float*)d_in[4];
  const float* w_hh_b = (const float*)d_in[5];
  const float* b_b    = (const float*)d_in[6];
  const float* W_lin  = (const float*)d_in[7];
  const float* b_lin  = (const float*)d_in[8];

  char* ws = (char*)d_ws;
  size_t off = 0;
  auto alloc = [&](size_t bytes) {
    char* p = ws + off;
    off = (off + bytes + 255) & ~(size_t)255;
    return p;
  };
  // ~112 MiB total
  u16* WIH2  = (u16*)alloc(6291456);   // [2048,1536]: rows 0..1023 F, 1024..2047 B; [W_hi|W_hi|W_lo]
  u16* WHHF  = (u16*)alloc(524288);    // [1024,256]
  u16* WHHB  = (u16*)alloc(524288);
  u16* WLIN  = (u16*)alloc(524288);    // [512,512]
  float* XPF = (float*)alloc(33554432);  // [64,128,1024] f32 (reused stage-3)
  float* XPB = (float*)alloc(33554432);
  u16* NIbf  = (u16*)alloc(8388608);   // [8192,512] bf16
  u16* HFfull = (u16*)alloc(4194304);  // [8192,256] (REC aliases HFfull+HBfull later)
  u16* HBfull = (u16*)alloc(4194304);
  u16* XH    = (u16*)alloc(25165824);  // [8192,1536] = [x_hi|x_lo|x_hi]
  u16* pA    = XH;                     // [8192,512] bf16 partial-max A (aliases dead XH)
  u16* pB    = XH + 4194304;           // [8192,512] bf16 partial-max B
  u16* REC   = HFfull;                 // [8192,512] aliases HFfull+HBfull

  split_input_kernel<<<dim3(4096), dim3(256), 0, stream>>>(input, XH, 4194304);
  split_w_kernel<<<dim3(2048), dim3(256), 0, stream>>>(w_ih_f, WIH2);
  split_w_kernel<<<dim3(2048), dim3(256), 0, stream>>>(w_ih_b, WIH2 + (size_t)1024 * 1536);
  cvt_bf16_kernel<<<dim3(256), dim3(256), 0, stream>>>(w_hh_f, WHHF, 65536);
  cvt_bf16_kernel<<<dim3(256), dim3(256), 0, stream>>>(w_hh_b, WHHB, 65536);
  cvt_bf16_kernel<<<dim3(256), dim3(256), 0, stream>>>(W_lin, WLIN, 65536);

  // stage-1 xp (split precision), merged F+B: N=2048, K=1536
  gemm_bt_kernel<<<dim3(16, 64), dim3(256), 0, stream>>>(XH, 1536, WIH2, 1536,
      b_f, b_b, XPF, XPB, 1024, 8192, 1536);

  // init partial-max buffers to bf16 -inf (0xFF80) — XH dead now
  fill_u32_kernel<<<dim3(2048), dim3(256), 0, stream>>>((u32*)pA, 0xFF80FF80u, 4194304);

  // stage-1 scans
  scan_kernel<<<dim3(208), dim3(512), 0, stream>>>(WHHF, WHHB, XPF, XPB, HFfull, HBfull, pA, pB, 1);

  // merge -> NI bf16
  finish_kernel<<<dim3(8192), dim3(512), 0, stream>>>(pA, pB, HFfull, HBfull, NIbf);

  // stage-3 xp, merged F+B: N=2048, K=512 (W_hi = first 512 cols of WIH2 rows)
  gemm_bt_kernel<<<dim3(16, 64), dim3(256), 0, stream>>>(NIbf, 512, WIH2, 1536,
      b_f, b_b, XPF, XPB, 1024, 8192, 512);

  // stage-3 bidirectional scan -> REC[bt][512]
  scan_kernel<<<dim3(8), dim3(512), 0, stream>>>(WHHF, WHHB, XPF, XPB, REC, REC + 256, pA, pB, 2);

  // output = REC @ W_lin^T + b_lin
  gemm_bt_kernel<<<dim3(4, 64), dim3(256), 0, stream>>>(REC, 512, WLIN, 512,
      b_lin, b_lin, (float*)d_out, (float*)d_out, 512, 8192, 512);
}